// Round 10
// baseline (114.483 us; speedup 1.0000x reference)
//
#include <hip/hip_runtime.h>
#include <hip/hip_bf16.h>

// Problem constants
#define NN 64
#define BB 256
#define DD 1792
#define KK 35
#define PP 10
#define DQ 448          // D / 4 (float4s per row)
#define RPW 4           // rows per wave
#define CH 7            // chunks per row (DQ / 64)

// PROVEN (R2-R7): 4-step row_shr DPP chain, bound_ctrl:0.
// Leaves the 16-lane-group sum in lane 15 of each group.
__device__ __forceinline__ float group16_sum_dpp(float x) {
    asm("v_add_f32_dpp %0, %0, %0 row_shr:1 row_mask:0xf bank_mask:0xf bound_ctrl:0" : "+v"(x));
    asm("v_add_f32_dpp %0, %0, %0 row_shr:2 row_mask:0xf bank_mask:0xf bound_ctrl:0" : "+v"(x));
    asm("v_add_f32_dpp %0, %0, %0 row_shr:4 row_mask:0xf bank_mask:0xf bound_ctrl:0" : "+v"(x));
    asm("v_add_f32_dpp %0, %0, %0 row_shr:8 row_mask:0xf bank_mask:0xf bound_ctrl:0" : "+v"(x));
    return x;
}

// All-lane wave64 sum built ONLY from proven primitives:
// group16 chain -> xor16 -> xor32 (lanes 15/31/47/63 hold total) -> bcast 63.
__device__ __forceinline__ float wave_allsum(float x) {
    x = group16_sum_dpp(x);
    x += __shfl_xor(x, 16);
    x += __shfl_xor(x, 32);
    return __shfl(x, 63);
}

// ---------------------------------------------------------------------------
// K1: Gf = gamma * W_net; sG[p] = sum(Gf[p]); zc[p] = dot(beta,Wnet[p]) + b_net[p]
// ---------------------------------------------------------------------------
__global__ void prep_gf(const float* __restrict__ gamma, const float* __restrict__ beta,
                        const float* __restrict__ Wnet, const float* __restrict__ bnet,
                        float* __restrict__ GF, float* __restrict__ SG, float* __restrict__ ZC) {
    const int p = blockIdx.x;
    const int tid = threadIdx.x;
    float sg = 0.f, sb = 0.f;
#pragma unroll
    for (int j = 0; j < 7; ++j) {
        int d = j * 256 + tid;
        float wv = Wnet[p * DD + d];
        float g = gamma[d] * wv;
        GF[p * DD + d] = g;
        sg += g;
        sb += beta[d] * wv;
    }
#pragma unroll
    for (int off = 32; off > 0; off >>= 1) {
        sg += __shfl_xor(sg, off);
        sb += __shfl_xor(sb, off);
    }
    __shared__ float rs[4][2];
    if ((tid & 63) == 0) { rs[tid >> 6][0] = sg; rs[tid >> 6][1] = sb; }
    __syncthreads();
    if (tid == 0) {
        float a = 0.f, c = 0.f;
#pragma unroll
        for (int w = 0; w < 4; ++w) { a += rs[w][0]; c += rs[w][1]; }
        SG[p] = a;
        ZC[p] = c + bnet[p];
    }
}

// ---------------------------------------------------------------------------
// K2: bank[b][r] = dot(task[b], Wtok[r]) + btok[r]; ptok[b][d] likewise.
// ---------------------------------------------------------------------------
__global__ void prep_bank(const float* __restrict__ task,
                          const float* __restrict__ Wtok, const float* __restrict__ btok,
                          const float* __restrict__ Wptok, const float* __restrict__ bptok,
                          float* __restrict__ bank, float* __restrict__ ptok) {
    __shared__ float ti[32 * KK];
    const int tid = threadIdx.x;
    const int b0 = blockIdx.y * 32;
    for (int i = tid; i < 32 * KK; i += 256) ti[i] = task[b0 * KK + i];

    const int r = blockIdx.x * 256 + tid;
    const bool isbank = (r < PP * DD);
    const int rr = isbank ? r : (r - PP * DD);
    const float* __restrict__ W = isbank ? Wtok : Wptok;
    const float bias = isbank ? btok[r] : bptok[rr];

    float w[KK];
#pragma unroll
    for (int k = 0; k < KK; ++k) w[k] = W[rr * KK + k];

    __syncthreads();
#pragma unroll 1
    for (int bb = 0; bb < 32; ++bb) {
        float acc = bias;
#pragma unroll
        for (int k = 0; k < KK; ++k) acc = fmaf(ti[bb * KK + k], w[k], acc);
        const int b = b0 + bb;
        if (isbank) bank[b * (PP * DD) + r] = acc;
        else        ptok[b * DD + rr]       = acc;
    }
}

// ---------------------------------------------------------------------------
// K3 (fused, wave-autonomous): each WAVE owns 4 complete (n,b) rows.
// Zero barriers, zero LDS tiles, zero inter-wave coupling.
// ---------------------------------------------------------------------------
__global__ __launch_bounds__(256) void fused_wave(
    const float* __restrict__ X, const float* __restrict__ BANK,
    const float* __restrict__ PTOK, const float* __restrict__ GF,
    const float* __restrict__ SG, const float* __restrict__ ZC,
    float* __restrict__ OUT) {
    const int tid  = threadIdx.x;
    const int lane = tid & 63;
    const int wid  = tid >> 6;
    const int bid  = blockIdx.x;
    const int b    = bid & (BB - 1);
    const int item = ((bid >> 8) << 2) + wid;   // 0..15
    const int n0   = item * RPW;

    const float4* __restrict__ X4 = (const float4*)X;
    const float4* __restrict__ B4 = (const float4*)BANK;
    const float4* __restrict__ G4 = (const float4*)GF;
    const float4* __restrict__ P4 = (const float4*)PTOK;
    float4* __restrict__ O4 = (float4*)OUT;

    const size_t rstr = (size_t)BB * DQ;                   // f4 stride per n-step
    const size_t x0   = ((size_t)n0 * BB + b) * DQ + lane; // chunk-0 f4 index
    const size_t pb   = (size_t)b * DQ + lane;

    float acc[RPW][12];
#pragma unroll
    for (int r = 0; r < RPW; ++r)
#pragma unroll
        for (int v = 0; v < 12; ++v) acc[r][v] = 0.f;

    // ---- phase 1: streaming stats ----
    float4 xv[2][RPW];
#pragma unroll
    for (int r = 0; r < RPW; ++r) xv[0][r] = X4[x0 + (size_t)r * rstr];

#pragma unroll
    for (int c = 0; c < CH; ++c) {
        const int cur = c & 1, nxt = cur ^ 1;
        // current-chunk gf/ptok (L2-resident, issued first)
        float4 gfv[PP];
#pragma unroll
        for (int p = 0; p < PP; ++p) gfv[p] = G4[(size_t)p * DQ + c * 64 + lane];
        const float4 pt = P4[pb + c * 64];
        // prefetch next X chunk (HBM) — issued last, stays in flight
        if (c < CH - 1) {
#pragma unroll
            for (int r = 0; r < RPW; ++r)
                xv[nxt][r] = X4[x0 + (c + 1) * 64 + (size_t)r * rstr];
        }
#pragma unroll
        for (int r = 0; r < RPW; ++r) {
            const float tx = xv[cur][r].x + pt.x;
            const float ty = xv[cur][r].y + pt.y;
            const float tz = xv[cur][r].z + pt.z;
            const float tw = xv[cur][r].w + pt.w;
            acc[r][0] += tx + ty + tz + tw;
            float s2 = fmaf(tx, tx, acc[r][1]);
            s2 = fmaf(ty, ty, s2); s2 = fmaf(tz, tz, s2); s2 = fmaf(tw, tw, s2);
            acc[r][1] = s2;
#pragma unroll
            for (int p = 0; p < PP; ++p) {
                float v = fmaf(tx, gfv[p].x, acc[r][2 + p]);
                v = fmaf(ty, gfv[p].y, v);
                v = fmaf(tz, gfv[p].z, v);
                v = fmaf(tw, gfv[p].w, v);
                acc[r][2 + p] = v;
            }
        }
    }

    // ---- wave-internal reduction (proven primitives only) ----
#pragma unroll
    for (int r = 0; r < RPW; ++r)
#pragma unroll
        for (int v = 0; v < 12; ++v) acc[r][v] = wave_allsum(acc[r][v]);

    // ---- weights (computed redundantly by all lanes) ----
    float wgt[RPW][PP];
#pragma unroll
    for (int r = 0; r < RPW; ++r) {
        const float mu   = acc[r][0] * (1.0f / (float)DD);
        const float ms   = acc[r][1] * (1.0f / (float)DD);
        const float istd = rsqrtf(ms - mu * mu + 1e-5f);
#pragma unroll
        for (int p = 0; p < PP; ++p) {
            const float z = istd * (acc[r][2 + p] - mu * SG[p]) + ZC[p];
            wgt[r][p] = 1.0f / (1.0f + __expf(-z));
        }
    }

    // ---- phase 2: out = X + w @ bank ----
    const size_t bb0 = (size_t)b * PP * DQ + lane;
    float4 x2[2][RPW];
#pragma unroll
    for (int r = 0; r < RPW; ++r) x2[0][r] = X4[x0 + (size_t)r * rstr];

#pragma unroll
    for (int c = 0; c < CH; ++c) {
        const int cur = c & 1, nxt = cur ^ 1;
        float4 bk[PP];
#pragma unroll
        for (int p = 0; p < PP; ++p) bk[p] = B4[bb0 + (size_t)p * DQ + c * 64];
        if (c < CH - 1) {
#pragma unroll
            for (int r = 0; r < RPW; ++r)
                x2[nxt][r] = X4[x0 + (c + 1) * 64 + (size_t)r * rstr];
        }
#pragma unroll
        for (int r = 0; r < RPW; ++r) {
            float4 o = x2[cur][r];
#pragma unroll
            for (int p = 0; p < PP; ++p) {
                o.x = fmaf(wgt[r][p], bk[p].x, o.x);
                o.y = fmaf(wgt[r][p], bk[p].y, o.y);
                o.z = fmaf(wgt[r][p], bk[p].z, o.z);
                o.w = fmaf(wgt[r][p], bk[p].w, o.w);
            }
            O4[x0 + c * 64 + (size_t)r * rstr] = o;
        }
    }
}

// ---------------------------------------------------------------------------
extern "C" void kernel_launch(void* const* d_in, const int* in_sizes, int n_in,
                              void* d_out, int out_size, void* d_ws, size_t ws_size,
                              hipStream_t stream) {
    const float* X     = (const float*)d_in[0];
    const float* task  = (const float*)d_in[1];
    const float* Wtok  = (const float*)d_in[2];
    const float* btok  = (const float*)d_in[3];
    const float* Wptok = (const float*)d_in[4];
    const float* bptok = (const float*)d_in[5];
    const float* gamma = (const float*)d_in[6];
    const float* beta  = (const float*)d_in[7];
    const float* Wnet  = (const float*)d_in[8];
    const float* bnet  = (const float*)d_in[9];
    float* out = (float*)d_out;

    float* ws = (float*)d_ws;
    float* bank = ws;                                  // B*P*D = 4,587,520
    float* ptok = bank + (size_t)BB * PP * DD;         // B*D   =   458,752
    float* GF   = ptok + (size_t)BB * DD;              // P*D   =    17,920
    float* SG   = GF + PP * DD;                        // P
    float* ZC   = SG + PP;                             // P

    prep_gf<<<PP, 256, 0, stream>>>(gamma, beta, Wnet, bnet, GF, SG, ZC);
    prep_bank<<<dim3(77, 8), 256, 0, stream>>>(task, Wtok, btok, Wptok, bptok, bank, ptok);
    fused_wave<<<1024, 256, 0, stream>>>(X, bank, ptok, GF, SG, ZC, out);
}

// Round 11
// 106.198 us; speedup vs baseline: 1.0780x; 1.0780x over previous
//
#include <hip/hip_runtime.h>
#include <hip/hip_bf16.h>

// Problem constants
#define NN 64
#define BB 256
#define DD 1792
#define KK 35
#define PP 10
#define DQ 448          // D / 4 (float4s per row)
#define NTILE 16        // n-rows per block (streaming loop length)
#define NG 28           // 16-lane groups per row (7 chunks x 4)

typedef float fx4 __attribute__((ext_vector_type(4)));

// PROVEN (R2-R8): 4-step row_shr DPP chain, bound_ctrl:0.
// Leaves the 16-lane-group sum in lane 15 of each group.
__device__ __forceinline__ float group16_sum_dpp(float x) {
    asm("v_add_f32_dpp %0, %0, %0 row_shr:1 row_mask:0xf bank_mask:0xf bound_ctrl:0" : "+v"(x));
    asm("v_add_f32_dpp %0, %0, %0 row_shr:2 row_mask:0xf bank_mask:0xf bound_ctrl:0" : "+v"(x));
    asm("v_add_f32_dpp %0, %0, %0 row_shr:4 row_mask:0xf bank_mask:0xf bound_ctrl:0" : "+v"(x));
    asm("v_add_f32_dpp %0, %0, %0 row_shr:8 row_mask:0xf bank_mask:0xf bound_ctrl:0" : "+v"(x));
    return x;
}

// ---------------------------------------------------------------------------
// K1: Gf = gamma * W_net; sG[p] = sum(Gf[p]); zc[p] = dot(beta,Wnet[p]) + b_net[p]
// ---------------------------------------------------------------------------
__global__ void prep_gf(const float* __restrict__ gamma, const float* __restrict__ beta,
                        const float* __restrict__ Wnet, const float* __restrict__ bnet,
                        float* __restrict__ GF, float* __restrict__ SG, float* __restrict__ ZC) {
    const int p = blockIdx.x;
    const int tid = threadIdx.x;
    float sg = 0.f, sb = 0.f;
#pragma unroll
    for (int j = 0; j < 7; ++j) {
        int d = j * 256 + tid;
        float wv = Wnet[p * DD + d];
        float g = gamma[d] * wv;
        GF[p * DD + d] = g;
        sg += g;
        sb += beta[d] * wv;
    }
#pragma unroll
    for (int off = 32; off > 0; off >>= 1) {
        sg += __shfl_xor(sg, off);
        sb += __shfl_xor(sb, off);
    }
    __shared__ float rs[4][2];
    if ((tid & 63) == 0) { rs[tid >> 6][0] = sg; rs[tid >> 6][1] = sb; }
    __syncthreads();
    if (tid == 0) {
        float a = 0.f, c = 0.f;
#pragma unroll
        for (int w = 0; w < 4; ++w) { a += rs[w][0]; c += rs[w][1]; }
        SG[p] = a;
        ZC[p] = c + bnet[p];
    }
}

// ---------------------------------------------------------------------------
// K2: bank[b][r] = dot(task[b], Wtok[r]) + btok[r]; ptok[b][d] likewise.
// ---------------------------------------------------------------------------
__global__ void prep_bank(const float* __restrict__ task,
                          const float* __restrict__ Wtok, const float* __restrict__ btok,
                          const float* __restrict__ Wptok, const float* __restrict__ bptok,
                          float* __restrict__ bank, float* __restrict__ ptok) {
    __shared__ float ti[32 * KK];
    const int tid = threadIdx.x;
    const int b0 = blockIdx.y * 32;
    for (int i = tid; i < 32 * KK; i += 256) ti[i] = task[b0 * KK + i];

    const int r = blockIdx.x * 256 + tid;
    const bool isbank = (r < PP * DD);
    const int rr = isbank ? r : (r - PP * DD);
    const float* __restrict__ W = isbank ? Wtok : Wptok;
    const float bias = isbank ? btok[r] : bptok[rr];

    float w[KK];
#pragma unroll
    for (int k = 0; k < KK; ++k) w[k] = W[rr * KK + k];

    __syncthreads();
#pragma unroll 1
    for (int bb = 0; bb < 32; ++bb) {
        float acc = bias;
#pragma unroll
        for (int k = 0; k < KK; ++k) acc = fmaf(ti[bb * KK + k], w[k], acc);
        const int b = b0 + bb;
        if (isbank) bank[b * (PP * DD) + r] = acc;
        else        ptok[b * DD + rr]       = acc;
    }
}

// ---------------------------------------------------------------------------
// K3 (weights_stream): block = (b, 16-n tile), 448 threads; wave = chunk c.
// gf/ptok slices in registers for the WHOLE kernel. Per n-iteration:
// 1 X float4 load (4-deep ring), 48 FMA, 12x group16 DPP, 3 predicated 16B
// partial stores (lanes 15/31/47/63 -> PART[row][group][12]).
// No LDS, no barriers, no cross-chunk combine, no per-chunk reload bursts.
// ---------------------------------------------------------------------------
__global__ __launch_bounds__(448) void weights_stream(
    const float* __restrict__ X, const float* __restrict__ PTOK,
    const float* __restrict__ GF, float* __restrict__ PART) {
    const int tid  = threadIdx.x;
    const int lane = tid & 63;
    const int c    = tid >> 6;            // chunk 0..6
    const int b    = blockIdx.x;
    const int n0   = blockIdx.y * NTILE;

    const float4* __restrict__ X4 = (const float4*)X;
    const float4* __restrict__ G4 = (const float4*)GF;
    const float4* __restrict__ P4 = (const float4*)PTOK;

    // persistent per-wave state
    float4 gfv[PP];
#pragma unroll
    for (int p = 0; p < PP; ++p) gfv[p] = G4[(size_t)p * DQ + c * 64 + lane];
    const float4 pt = P4[(size_t)b * DQ + c * 64 + lane];

    const int  g      = c * 4 + (lane >> 4);       // group 0..27
    const bool writer = ((lane & 15) == 15);

    const size_t rstr = (size_t)BB * DQ;
    const size_t base = ((size_t)n0 * BB + b) * DQ + c * 64 + lane;

    float4 ring[4];
#pragma unroll
    for (int j = 0; j < 4; ++j) ring[j] = X4[base + (size_t)j * rstr];

#pragma unroll
    for (int r = 0; r < NTILE; ++r) {
        float4 x = ring[r & 3];
        if (r < NTILE - 4) ring[r & 3] = X4[base + (size_t)(r + 4) * rstr];

        const float tx = x.x + pt.x;
        const float ty = x.y + pt.y;
        const float tz = x.z + pt.z;
        const float tw = x.w + pt.w;

        float s1 = tx + ty + tz + tw;
        float s2 = tx * tx;
        s2 = fmaf(ty, ty, s2); s2 = fmaf(tz, tz, s2); s2 = fmaf(tw, tw, s2);
        float a[PP];
#pragma unroll
        for (int p = 0; p < PP; ++p) {
            float v = tx * gfv[p].x;
            v = fmaf(ty, gfv[p].y, v);
            v = fmaf(tz, gfv[p].z, v);
            v = fmaf(tw, gfv[p].w, v);
            a[p] = v;
        }
        s1 = group16_sum_dpp(s1);
        s2 = group16_sum_dpp(s2);
#pragma unroll
        for (int p = 0; p < PP; ++p) a[p] = group16_sum_dpp(a[p]);

        if (writer) {
            float4* dst = (float4*)(PART + (((size_t)(n0 + r) * BB + b) * NG + g) * 12);
            dst[0] = make_float4(s1, s2, a[0], a[1]);
            dst[1] = make_float4(a[2], a[3], a[4], a[5]);
            dst[2] = make_float4(a[6], a[7], a[8], a[9]);
        }
    }
}

// ---------------------------------------------------------------------------
// K4 (finalize_w): sum 28 group-partials per row, sigmoid, write w[n][b][12].
// Wave handles 16 rows: lane = (row<<2)|sub; lane sums groups sub,sub+4,..;
// xor-reduce over sub; sub==0 computes 10 sigmoids and stores 48 B.
// ---------------------------------------------------------------------------
__global__ __launch_bounds__(256) void finalize_w(
    const float* __restrict__ PART, const float* __restrict__ SG,
    const float* __restrict__ ZC, float* __restrict__ Wout) {
    const int tid  = threadIdx.x;
    const int lane = tid & 63;
    const int wv   = tid >> 6;
    const size_t row = (size_t)blockIdx.x * 64 + wv * 16 + (lane >> 2);
    const int sub  = lane & 3;

    float s[12];
#pragma unroll
    for (int v = 0; v < 12; ++v) s[v] = 0.f;

#pragma unroll
    for (int j = 0; j < 7; ++j) {
        const int g = sub + j * 4;
        const float4* src = (const float4*)(PART + (row * NG + g) * 12);
        float4 u0 = src[0], u1 = src[1], u2 = src[2];
        s[0] += u0.x; s[1] += u0.y; s[2]  += u0.z; s[3]  += u0.w;
        s[4] += u1.x; s[5] += u1.y; s[6]  += u1.z; s[7]  += u1.w;
        s[8] += u2.x; s[9] += u2.y; s[10] += u2.z; s[11] += u2.w;
    }
#pragma unroll
    for (int v = 0; v < 12; ++v) {
        s[v] += __shfl_xor(s[v], 1);
        s[v] += __shfl_xor(s[v], 2);
    }
    if (sub == 0) {
        const float mu   = s[0] * (1.0f / (float)DD);
        const float ms   = s[1] * (1.0f / (float)DD);
        const float istd = rsqrtf(ms - mu * mu + 1e-5f);
        float w[PP];
#pragma unroll
        for (int p = 0; p < PP; ++p) {
            const float z = istd * (s[2 + p] - mu * SG[p]) + ZC[p];
            w[p] = 1.0f / (1.0f + __expf(-z));
        }
        float4* dst = (float4*)(Wout + row * 12);
        dst[0] = make_float4(w[0], w[1], w[2], w[3]);
        dst[1] = make_float4(w[4], w[5], w[6], w[7]);
        dst[2] = make_float4(w[8], w[9], 0.f, 0.f);
    }
}

// ---------------------------------------------------------------------------
// K5 (apply_stream): block = (b, 16-n tile), 448 threads; wave = chunk c.
// bank slice (10 f4) in registers for the WHOLE kernel. Per n-iteration:
// 1 X load (4-deep ring) + 10 uniform w loads (scalar, L1) + 40 FMA +
// 1 nontemporal store. No LDS, no barriers.
// ---------------------------------------------------------------------------
__global__ __launch_bounds__(448) void apply_stream(
    const float* __restrict__ X, const float* __restrict__ BANK,
    const float* __restrict__ W, float* __restrict__ OUT) {
    const int tid  = threadIdx.x;
    const int lane = tid & 63;
    const int c    = tid >> 6;
    const int b    = blockIdx.x;
    const int n0   = blockIdx.y * NTILE;

    const float4* __restrict__ X4 = (const float4*)X;
    const float4* __restrict__ B4 = (const float4*)BANK;
    fx4* __restrict__ O4 = (fx4*)OUT;

    float4 bk[PP];
#pragma unroll
    for (int p = 0; p < PP; ++p) bk[p] = B4[((size_t)b * PP + p) * DQ + c * 64 + lane];

    const size_t rstr = (size_t)BB * DQ;
    const size_t base = ((size_t)n0 * BB + b) * DQ + c * 64 + lane;

    float4 ring[4];
#pragma unroll
    for (int j = 0; j < 4; ++j) ring[j] = X4[base + (size_t)j * rstr];

#pragma unroll
    for (int r = 0; r < NTILE; ++r) {
        float4 x = ring[r & 3];
        if (r < NTILE - 4) ring[r & 3] = X4[base + (size_t)(r + 4) * rstr];

        const float* __restrict__ wr = W + ((size_t)(n0 + r) * BB + b) * 12;  // uniform
        float wv[PP];
#pragma unroll
        for (int p = 0; p < PP; ++p) wv[p] = wr[p];

        float4 acc = x;
#pragma unroll
        for (int p = 0; p < PP; ++p) {
            acc.x = fmaf(wv[p], bk[p].x, acc.x);
            acc.y = fmaf(wv[p], bk[p].y, acc.y);
            acc.z = fmaf(wv[p], bk[p].z, acc.z);
            acc.w = fmaf(wv[p], bk[p].w, acc.w);
        }
        fx4 av;
        av.x = acc.x; av.y = acc.y; av.z = acc.z; av.w = acc.w;
        __builtin_nontemporal_store(av, &O4[base + (size_t)r * rstr]);
    }
}

// ---------------------------------------------------------------------------
extern "C" void kernel_launch(void* const* d_in, const int* in_sizes, int n_in,
                              void* d_out, int out_size, void* d_ws, size_t ws_size,
                              hipStream_t stream) {
    const float* X     = (const float*)d_in[0];
    const float* task  = (const float*)d_in[1];
    const float* Wtok  = (const float*)d_in[2];
    const float* btok  = (const float*)d_in[3];
    const float* Wptok = (const float*)d_in[4];
    const float* bptok = (const float*)d_in[5];
    const float* gamma = (const float*)d_in[6];
    const float* beta  = (const float*)d_in[7];
    const float* Wnet  = (const float*)d_in[8];
    const float* bnet  = (const float*)d_in[9];
    float* out = (float*)d_out;

    float* ws   = (float*)d_ws;
    float* bank = ws;                                  // B*P*D   = 4,587,520
    float* ptok = bank + (size_t)BB * PP * DD;         // B*D     =   458,752
    float* GF   = ptok + (size_t)BB * DD;              // P*D     =    17,920
    float* SG   = GF + PP * DD;                        // P
    float* ZC   = SG + PP;                             // P
    float* Wout = ZC + PP;                             // N*B*12  =   196,608
    float* PART = Wout + (size_t)NN * BB * 12;         // N*B*28*12 = 5,505,024

    prep_gf<<<PP, 256, 0, stream>>>(gamma, beta, Wnet, bnet, GF, SG, ZC);
    prep_bank<<<dim3(77, 8), 256, 0, stream>>>(task, Wtok, btok, Wptok, bptok, bank, ptok);
    weights_stream<<<dim3(BB, NN / NTILE), 448, 0, stream>>>(X, ptok, GF, PART);
    finalize_w<<<(NN * BB) / 64, 256, 0, stream>>>(PART, SG, ZC, Wout);
    apply_stream<<<dim3(BB, NN / NTILE), 448, 0, stream>>>(X, bank, Wout, out);
}

// Round 12
// 97.855 us; speedup vs baseline: 1.1699x; 1.0853x over previous
//
#include <hip/hip_runtime.h>
#include <hip/hip_bf16.h>

// Problem constants
#define NN 64
#define BB 256
#define DD 1792
#define KK 35
#define PP 10
#define DQ 448          // D / 4 (float4s per row)
#define FR 8            // rows per fused-block
#define NGRP 28         // 16-lane groups per 448-thread block

// PROVEN (R2-R8): 4-step row_shr DPP chain, bound_ctrl:0.
// Leaves the 16-lane-group sum in lane 15 of each group.
__device__ __forceinline__ float group16_sum_dpp(float x) {
    asm("v_add_f32_dpp %0, %0, %0 row_shr:1 row_mask:0xf bank_mask:0xf bound_ctrl:0" : "+v"(x));
    asm("v_add_f32_dpp %0, %0, %0 row_shr:2 row_mask:0xf bank_mask:0xf bound_ctrl:0" : "+v"(x));
    asm("v_add_f32_dpp %0, %0, %0 row_shr:4 row_mask:0xf bank_mask:0xf bound_ctrl:0" : "+v"(x));
    asm("v_add_f32_dpp %0, %0, %0 row_shr:8 row_mask:0xf bank_mask:0xf bound_ctrl:0" : "+v"(x));
    return x;
}

// ---------------------------------------------------------------------------
// K1: Gf = gamma * W_net; sG[p] = sum(Gf[p]); zc[p] = dot(beta,Wnet[p]) + b_net[p]
// ---------------------------------------------------------------------------
__global__ void prep_gf(const float* __restrict__ gamma, const float* __restrict__ beta,
                        const float* __restrict__ Wnet, const float* __restrict__ bnet,
                        float* __restrict__ GF, float* __restrict__ SG, float* __restrict__ ZC) {
    const int p = blockIdx.x;
    const int tid = threadIdx.x;
    float sg = 0.f, sb = 0.f;
#pragma unroll
    for (int j = 0; j < 7; ++j) {
        int d = j * 256 + tid;
        float wv = Wnet[p * DD + d];
        float g = gamma[d] * wv;
        GF[p * DD + d] = g;
        sg += g;
        sb += beta[d] * wv;
    }
#pragma unroll
    for (int off = 32; off > 0; off >>= 1) {
        sg += __shfl_xor(sg, off);
        sb += __shfl_xor(sb, off);
    }
    __shared__ float rs[4][2];
    if ((tid & 63) == 0) { rs[tid >> 6][0] = sg; rs[tid >> 6][1] = sb; }
    __syncthreads();
    if (tid == 0) {
        float a = 0.f, c = 0.f;
#pragma unroll
        for (int w = 0; w < 4; ++w) { a += rs[w][0]; c += rs[w][1]; }
        SG[p] = a;
        ZC[p] = c + bnet[p];
    }
}

// ---------------------------------------------------------------------------
// K2: bank[b][r] = dot(task[b], Wtok[r]) + btok[r]; ptok[b][d] likewise.
// ---------------------------------------------------------------------------
__global__ void prep_bank(const float* __restrict__ task,
                          const float* __restrict__ Wtok, const float* __restrict__ btok,
                          const float* __restrict__ Wptok, const float* __restrict__ bptok,
                          float* __restrict__ bank, float* __restrict__ ptok) {
    __shared__ float ti[32 * KK];
    const int tid = threadIdx.x;
    const int b0 = blockIdx.y * 32;
    for (int i = tid; i < 32 * KK; i += 256) ti[i] = task[b0 * KK + i];

    const int r = blockIdx.x * 256 + tid;
    const bool isbank = (r < PP * DD);
    const int rr = isbank ? r : (r - PP * DD);
    const float* __restrict__ W = isbank ? Wtok : Wptok;
    const float bias = isbank ? btok[r] : bptok[rr];

    float w[KK];
#pragma unroll
    for (int k = 0; k < KK; ++k) w[k] = W[rr * KK + k];

    __syncthreads();
#pragma unroll 1
    for (int bb = 0; bb < 32; ++bb) {
        float acc = bias;
#pragma unroll
        for (int k = 0; k < KK; ++k) acc = fmaf(ti[bb * KK + k], w[k], acc);
        const int b = b0 + bb;
        if (isbank) bank[b * (PP * DD) + r] = acc;
        else        ptok[b * DD + rr]       = acc;
    }
}

// ---------------------------------------------------------------------------
// K3 (fused, R8 structure + FORCED MLP): per block (b, 8 rows), 448 threads.
// Load clusters pinned with sched_barrier(0) so the compiler cannot sink
// loads to their uses: ptk+gf (L2) -> 8 X rows (HBM) -> 10 bank rows (L3),
// 29 loads in flight per wave. Then phase 1 consume (X in regs), one
// barrier, finalize, one barrier, phase 2 fma+store from registers.
// ---------------------------------------------------------------------------
__global__ __launch_bounds__(448) void fused_kernel(
    const float* __restrict__ X, const float* __restrict__ BANK,
    const float* __restrict__ PTOK, const float* __restrict__ GF,
    const float* __restrict__ SG, const float* __restrict__ ZC,
    float* __restrict__ OUT) {
    const int tid = threadIdx.x;
    const int b = blockIdx.y;
    const int n0 = blockIdx.x * FR;

    const float4* __restrict__ X4 = (const float4*)X;
    const float4* __restrict__ B4 = (const float4*)BANK;
    const float4* __restrict__ G4 = (const float4*)GF;
    const float4* __restrict__ P4 = (const float4*)PTOK;
    float4* __restrict__ O4 = (float4*)OUT;

    __shared__ float red[FR][NGRP][12];
    __shared__ float wlds[FR][PP];

    const size_t rstride = (size_t)BB * DQ;
    const size_t idx0 = ((size_t)n0 * BB + b) * DQ + tid;

    // ---- load cluster 1: ptok + gf (L2-resident) ----
    const float4 ptk = P4[(size_t)b * DQ + tid];
    float4 gf[PP];
#pragma unroll
    for (int p = 0; p < PP; ++p) gf[p] = G4[(size_t)p * DQ + tid];
    __builtin_amdgcn_sched_barrier(0);

    // ---- load cluster 2: all 8 X rows (HBM) ----
    float4 x[FR];
#pragma unroll
    for (int r = 0; r < FR; ++r) x[r] = X4[idx0 + (size_t)r * rstride];
    __builtin_amdgcn_sched_barrier(0);

    // ---- load cluster 3: all 10 bank rows (L3; consumed in phase 2) ----
    float4 bk[PP];
#pragma unroll
    for (int p = 0; p < PP; ++p) bk[p] = B4[((size_t)b * PP + p) * DQ + tid];
    __builtin_amdgcn_sched_barrier(0);

    const bool writer = ((tid & 15) == 15);
    const int g = tid >> 4;

    // ---- phase 1 ----
#pragma unroll
    for (int r = 0; r < FR; ++r) {
        float4 t;
        t.x = x[r].x + ptk.x; t.y = x[r].y + ptk.y;
        t.z = x[r].z + ptk.z; t.w = x[r].w + ptk.w;

        float s1 = t.x + t.y + t.z + t.w;
        float s2 = t.x * t.x;
        s2 = fmaf(t.y, t.y, s2); s2 = fmaf(t.z, t.z, s2); s2 = fmaf(t.w, t.w, s2);
        float a[PP];
#pragma unroll
        for (int p = 0; p < PP; ++p) {
            float v = t.x * gf[p].x;
            v = fmaf(t.y, gf[p].y, v);
            v = fmaf(t.z, gf[p].z, v);
            v = fmaf(t.w, gf[p].w, v);
            a[p] = v;
        }
        s1 = group16_sum_dpp(s1);
        s2 = group16_sum_dpp(s2);
#pragma unroll
        for (int p = 0; p < PP; ++p) a[p] = group16_sum_dpp(a[p]);

        if (writer) {
            float4* dst = (float4*)&red[r][g][0];
            dst[0] = make_float4(s1, s2, a[0], a[1]);
            dst[1] = make_float4(a[2], a[3], a[4], a[5]);
            dst[2] = make_float4(a[6], a[7], a[8], a[9]);
        }
    }

    __syncthreads();

    // ---- finalize 8 rows' weights (128 threads) ----
    if (tid < FR * 16) {
        const int row = tid >> 4;
        const int v = tid & 15;
        float f = 0.f;
        if (v < 12) {
#pragma unroll
            for (int q = 0; q < NGRP; ++q) f += red[row][q][v];
        }
        const int base = (tid & 63) & ~15;
        const float mu = __shfl(f, base)     * (1.0f / (float)DD);
        const float ms = __shfl(f, base + 1) * (1.0f / (float)DD);
        const float istd = rsqrtf(ms - mu * mu + 1e-5f);
        if (v >= 2 && v < 12) {
            const int p = v - 2;
            const float z = istd * (f - mu * SG[p]) + ZC[p];
            wlds[row][p] = 1.0f / (1.0f + __expf(-z));
        }
    }
    __syncthreads();

    // ---- phase 2: out = x + w @ bank, straight from registers ----
#pragma unroll
    for (int r = 0; r < FR; ++r) {
        float4 acc = x[r];
#pragma unroll
        for (int p = 0; p < PP; ++p) {
            const float wv = wlds[r][p];
            acc.x = fmaf(wv, bk[p].x, acc.x);
            acc.y = fmaf(wv, bk[p].y, acc.y);
            acc.z = fmaf(wv, bk[p].z, acc.z);
            acc.w = fmaf(wv, bk[p].w, acc.w);
        }
        O4[idx0 + (size_t)r * rstride] = acc;
    }
}

// ---------------------------------------------------------------------------
extern "C" void kernel_launch(void* const* d_in, const int* in_sizes, int n_in,
                              void* d_out, int out_size, void* d_ws, size_t ws_size,
                              hipStream_t stream) {
    const float* X     = (const float*)d_in[0];
    const float* task  = (const float*)d_in[1];
    const float* Wtok  = (const float*)d_in[2];
    const float* btok  = (const float*)d_in[3];
    const float* Wptok = (const float*)d_in[4];
    const float* bptok = (const float*)d_in[5];
    const float* gamma = (const float*)d_in[6];
    const float* beta  = (const float*)d_in[7];
    const float* Wnet  = (const float*)d_in[8];
    const float* bnet  = (const float*)d_in[9];
    float* out = (float*)d_out;

    float* ws = (float*)d_ws;
    float* bank = ws;                                  // B*P*D = 4,587,520
    float* ptok = bank + (size_t)BB * PP * DD;         // B*D   =   458,752
    float* GF   = ptok + (size_t)BB * DD;              // P*D   =    17,920
    float* SG   = GF + PP * DD;                        // P
    float* ZC   = SG + PP;                             // P

    prep_gf<<<PP, 256, 0, stream>>>(gamma, beta, Wnet, bnet, GF, SG, ZC);
    prep_bank<<<dim3(77, 8), 256, 0, stream>>>(task, Wtok, btok, Wptok, bptok, bank, ptok);
    fused_kernel<<<dim3(NN / FR, BB), 448, 0, stream>>>(X, bank, ptok, GF, SG, ZC, out);
}

// Round 13
// 93.619 us; speedup vs baseline: 1.2229x; 1.0452x over previous
//
#include <hip/hip_runtime.h>
#include <hip/hip_bf16.h>

// Problem constants
#define NN 64
#define BB 256
#define DD 1792
#define KK 35
#define PP 10
#define DQ 448          // D / 4 (float4s per row)
#define FR 8            // rows per fused-block
#define NGRP 28         // 16-lane groups per 448-thread block

// PROVEN (R2-R8): 4-step row_shr DPP chain, bound_ctrl:0.
// Leaves the 16-lane-group sum in lane 15 of each group.
__device__ __forceinline__ float group16_sum_dpp(float x) {
    asm("v_add_f32_dpp %0, %0, %0 row_shr:1 row_mask:0xf bank_mask:0xf bound_ctrl:0" : "+v"(x));
    asm("v_add_f32_dpp %0, %0, %0 row_shr:2 row_mask:0xf bank_mask:0xf bound_ctrl:0" : "+v"(x));
    asm("v_add_f32_dpp %0, %0, %0 row_shr:4 row_mask:0xf bank_mask:0xf bound_ctrl:0" : "+v"(x));
    asm("v_add_f32_dpp %0, %0, %0 row_shr:8 row_mask:0xf bank_mask:0xf bound_ctrl:0" : "+v"(x));
    return x;
}

// ---------------------------------------------------------------------------
// K1: Gf = gamma * W_net; sG[p] = sum(Gf[p]); zc[p] = dot(beta,Wnet[p]) + b_net[p]
// ---------------------------------------------------------------------------
__global__ void prep_gf(const float* __restrict__ gamma, const float* __restrict__ beta,
                        const float* __restrict__ Wnet, const float* __restrict__ bnet,
                        float* __restrict__ GF, float* __restrict__ SG, float* __restrict__ ZC) {
    const int p = blockIdx.x;
    const int tid = threadIdx.x;
    float sg = 0.f, sb = 0.f;
#pragma unroll
    for (int j = 0; j < 7; ++j) {
        int d = j * 256 + tid;
        float wv = Wnet[p * DD + d];
        float g = gamma[d] * wv;
        GF[p * DD + d] = g;
        sg += g;
        sb += beta[d] * wv;
    }
#pragma unroll
    for (int off = 32; off > 0; off >>= 1) {
        sg += __shfl_xor(sg, off);
        sb += __shfl_xor(sb, off);
    }
    __shared__ float rs[4][2];
    if ((tid & 63) == 0) { rs[tid >> 6][0] = sg; rs[tid >> 6][1] = sb; }
    __syncthreads();
    if (tid == 0) {
        float a = 0.f, c = 0.f;
#pragma unroll
        for (int w = 0; w < 4; ++w) { a += rs[w][0]; c += rs[w][1]; }
        SG[p] = a;
        ZC[p] = c + bnet[p];
    }
}

// ---------------------------------------------------------------------------
// K2: bank[b][r] = dot(task[b], Wtok[r]) + btok[r]; ptok[b][d] likewise.
// ---------------------------------------------------------------------------
__global__ void prep_bank(const float* __restrict__ task,
                          const float* __restrict__ Wtok, const float* __restrict__ btok,
                          const float* __restrict__ Wptok, const float* __restrict__ bptok,
                          float* __restrict__ bank, float* __restrict__ ptok) {
    __shared__ float ti[32 * KK];
    const int tid = threadIdx.x;
    const int b0 = blockIdx.y * 32;
    for (int i = tid; i < 32 * KK; i += 256) ti[i] = task[b0 * KK + i];

    const int r = blockIdx.x * 256 + tid;
    const bool isbank = (r < PP * DD);
    const int rr = isbank ? r : (r - PP * DD);
    const float* __restrict__ W = isbank ? Wtok : Wptok;
    const float bias = isbank ? btok[r] : bptok[rr];

    float w[KK];
#pragma unroll
    for (int k = 0; k < KK; ++k) w[k] = W[rr * KK + k];

    __syncthreads();
#pragma unroll 1
    for (int bb = 0; bb < 32; ++bb) {
        float acc = bias;
#pragma unroll
        for (int k = 0; k < KK; ++k) acc = fmaf(ti[bb * KK + k], w[k], acc);
        const int b = b0 + bb;
        if (isbank) bank[b * (PP * DD) + r] = acc;
        else        ptok[b * DD + rr]       = acc;
    }
}

// ---------------------------------------------------------------------------
// K3 (fused, LDS-staged): per block (b, 8 rows), 448 threads (7 waves = 7
// chunks). X staged via async global_load_lds (NO dest VGPRs -> compiler
// cannot serialize; 8x1KB per wave, 57KB per block guaranteed in flight).
// One vmcnt(0) drain, then phase 1 from LDS (each wave reads only its own
// staged chunk), raw s_barrier (+lgkmcnt only, no vmcnt drain), finalize,
// raw s_barrier, phase 2 from LDS (X never re-touches HBM).
// LDS 68.4 KB -> 2 blocks/CU co-resident.
// ---------------------------------------------------------------------------
__global__ __launch_bounds__(448) void fused_kernel(
    const float* __restrict__ X, const float* __restrict__ BANK,
    const float* __restrict__ PTOK, const float* __restrict__ GF,
    const float* __restrict__ SG, const float* __restrict__ ZC,
    float* __restrict__ OUT) {
    const int tid  = threadIdx.x;
    const int lane = tid & 63;
    const int c    = tid >> 6;          // chunk 0..6
    const int b    = blockIdx.y;
    const int n0   = blockIdx.x * FR;

    const float4* __restrict__ X4 = (const float4*)X;
    const float4* __restrict__ B4 = (const float4*)BANK;
    const float4* __restrict__ G4 = (const float4*)GF;
    const float4* __restrict__ P4 = (const float4*)PTOK;
    float4* __restrict__ O4 = (float4*)OUT;

    __shared__ float xbuf[FR][DD];        // 57344 B
    __shared__ float red[FR][NGRP][12];   // 10752 B
    __shared__ float wlds[FR][PP];        //   320 B

    const size_t rstride = (size_t)BB * DQ;
    const size_t g0 = ((size_t)n0 * BB + b) * DQ + c * 64 + lane;

    // ---- stage cluster: FIRST vmem ops of the kernel, no dest regs ----
#pragma unroll
    for (int r = 0; r < FR; ++r) {
        const float4* src = X4 + g0 + (size_t)r * rstride;
        __builtin_amdgcn_global_load_lds(
            (const __attribute__((address_space(1))) void*)src,
            (__attribute__((address_space(3))) void*)&xbuf[r][c * 256],
            16, 0, 0);
    }
    __builtin_amdgcn_sched_barrier(0);

    // ---- register loads (issued after stages; L2/L3-resident) ----
    const float4 ptk = P4[(size_t)b * DQ + c * 64 + lane];
    float4 gf[PP];
#pragma unroll
    for (int p = 0; p < PP; ++p) gf[p] = G4[(size_t)p * DQ + c * 64 + lane];
    float4 bk[PP];
#pragma unroll
    for (int p = 0; p < PP; ++p) bk[p] = B4[((size_t)b * PP + p) * DQ + c * 64 + lane];
    __builtin_amdgcn_sched_barrier(0);

    // ---- single drain: all stages (and reg loads) complete ----
    asm volatile("s_waitcnt vmcnt(0)" ::: "memory");
    __builtin_amdgcn_sched_barrier(0);

    const bool writer = ((lane & 15) == 15);
    const int g = tid >> 4;

    // ---- phase 1: from LDS (own wave's staged chunk only) ----
#pragma unroll
    for (int r = 0; r < FR; ++r) {
        const float4 x = *(const float4*)&xbuf[r][c * 256 + lane * 4];
        float4 t;
        t.x = x.x + ptk.x; t.y = x.y + ptk.y;
        t.z = x.z + ptk.z; t.w = x.w + ptk.w;

        float s1 = t.x + t.y + t.z + t.w;
        float s2 = t.x * t.x;
        s2 = fmaf(t.y, t.y, s2); s2 = fmaf(t.z, t.z, s2); s2 = fmaf(t.w, t.w, s2);
        float a[PP];
#pragma unroll
        for (int p = 0; p < PP; ++p) {
            float v = t.x * gf[p].x;
            v = fmaf(t.y, gf[p].y, v);
            v = fmaf(t.z, gf[p].z, v);
            v = fmaf(t.w, gf[p].w, v);
            a[p] = v;
        }
        s1 = group16_sum_dpp(s1);
        s2 = group16_sum_dpp(s2);
#pragma unroll
        for (int p = 0; p < PP; ++p) a[p] = group16_sum_dpp(a[p]);

        if (writer) {
            float4* dst = (float4*)&red[r][g][0];
            dst[0] = make_float4(s1, s2, a[0], a[1]);
            dst[1] = make_float4(a[2], a[3], a[4], a[5]);
            dst[2] = make_float4(a[6], a[7], a[8], a[9]);
        }
    }

    // ---- raw barrier #1 (lgkm drain only — no vmcnt) ----
    asm volatile("s_waitcnt lgkmcnt(0)" ::: "memory");
    __builtin_amdgcn_sched_barrier(0);
    __builtin_amdgcn_s_barrier();
    __builtin_amdgcn_sched_barrier(0);

    // ---- finalize 8 rows' weights (first 128 threads) ----
    if (tid < FR * 16) {
        const int row = tid >> 4;
        const int v = tid & 15;
        float f = 0.f;
        if (v < 12) {
#pragma unroll
            for (int q = 0; q < NGRP; ++q) f += red[row][q][v];
        }
        const int base = (tid & 63) & ~15;
        const float mu = __shfl(f, base)     * (1.0f / (float)DD);
        const float ms = __shfl(f, base + 1) * (1.0f / (float)DD);
        const float istd = rsqrtf(ms - mu * mu + 1e-5f);
        if (v >= 2 && v < 12) {
            const int p = v - 2;
            const float z = istd * (f - mu * SG[p]) + ZC[p];
            wlds[row][p] = 1.0f / (1.0f + __expf(-z));
        }
    }

    // ---- raw barrier #2 ----
    asm volatile("s_waitcnt lgkmcnt(0)" ::: "memory");
    __builtin_amdgcn_sched_barrier(0);
    __builtin_amdgcn_s_barrier();
    __builtin_amdgcn_sched_barrier(0);

    // ---- phase 2: out = x(LDS) + w @ bank(regs) ----
#pragma unroll
    for (int r = 0; r < FR; ++r) {
        const float4 x = *(const float4*)&xbuf[r][c * 256 + lane * 4];
        float4 acc = x;
#pragma unroll
        for (int p = 0; p < PP; ++p) {
            const float wv = wlds[r][p];
            acc.x = fmaf(wv, bk[p].x, acc.x);
            acc.y = fmaf(wv, bk[p].y, acc.y);
            acc.z = fmaf(wv, bk[p].z, acc.z);
            acc.w = fmaf(wv, bk[p].w, acc.w);
        }
        O4[g0 + (size_t)r * rstride] = acc;
    }
}

// ---------------------------------------------------------------------------
extern "C" void kernel_launch(void* const* d_in, const int* in_sizes, int n_in,
                              void* d_out, int out_size, void* d_ws, size_t ws_size,
                              hipStream_t stream) {
    const float* X     = (const float*)d_in[0];
    const float* task  = (const float*)d_in[1];
    const float* Wtok  = (const float*)d_in[2];
    const float* btok  = (const float*)d_in[3];
    const float* Wptok = (const float*)d_in[4];
    const float* bptok = (const float*)d_in[5];
    const float* gamma = (const float*)d_in[6];
    const float* beta  = (const float*)d_in[7];
    const float* Wnet  = (const float*)d_in[8];
    const float* bnet  = (const float*)d_in[9];
    float* out = (float*)d_out;

    float* ws = (float*)d_ws;
    float* bank = ws;                                  // B*P*D = 4,587,520
    float* ptok = bank + (size_t)BB * PP * DD;         // B*D   =   458,752
    float* GF   = ptok + (size_t)BB * DD;              // P*D   =    17,920
    float* SG   = GF + PP * DD;                        // P
    float* ZC   = SG + PP;                             // P

    prep_gf<<<PP, 256, 0, stream>>>(gamma, beta, Wnet, bnet, GF, SG, ZC);
    prep_bank<<<dim3(77, 8), 256, 0, stream>>>(task, Wtok, btok, Wptok, bptok, bank, ptok);
    fused_kernel<<<dim3(NN / FR, BB), 448, 0, stream>>>(X, bank, ptok, GF, SG, ZC, out);
}

// Round 15
// 78.877 us; speedup vs baseline: 1.4514x; 1.1869x over previous
//
#include <hip/hip_runtime.h>
#include <hip/hip_bf16.h>

// Problem constants
#define NN 64
#define BB 256
#define DD 1792
#define KK 35
#define PP 10
#define DQ 448          // D / 4 (float4s per row)
#define GR 8            // rows per group
#define NGRP 28         // 16-lane groups per 448-thread block

// PROVEN (R2-R8): 4-step row_shr DPP chain, bound_ctrl:0.
// Leaves the 16-lane-group sum in lane 15 of each group.
__device__ __forceinline__ float group16_sum_dpp(float x) {
    asm("v_add_f32_dpp %0, %0, %0 row_shr:1 row_mask:0xf bank_mask:0xf bound_ctrl:0" : "+v"(x));
    asm("v_add_f32_dpp %0, %0, %0 row_shr:2 row_mask:0xf bank_mask:0xf bound_ctrl:0" : "+v"(x));
    asm("v_add_f32_dpp %0, %0, %0 row_shr:4 row_mask:0xf bank_mask:0xf bound_ctrl:0" : "+v"(x));
    asm("v_add_f32_dpp %0, %0, %0 row_shr:8 row_mask:0xf bank_mask:0xf bound_ctrl:0" : "+v"(x));
    return x;
}

// ---------------------------------------------------------------------------
// K1: Gf = gamma * W_net; sG[p] = sum(Gf[p]); zc[p] = dot(beta,Wnet[p]) + b_net[p]
// ---------------------------------------------------------------------------
__global__ void prep_gf(const float* __restrict__ gamma, const float* __restrict__ beta,
                        const float* __restrict__ Wnet, const float* __restrict__ bnet,
                        float* __restrict__ GF, float* __restrict__ SG, float* __restrict__ ZC) {
    const int p = blockIdx.x;
    const int tid = threadIdx.x;
    float sg = 0.f, sb = 0.f;
#pragma unroll
    for (int j = 0; j < 7; ++j) {
        int d = j * 256 + tid;
        float wv = Wnet[p * DD + d];
        float g = gamma[d] * wv;
        GF[p * DD + d] = g;
        sg += g;
        sb += beta[d] * wv;
    }
#pragma unroll
    for (int off = 32; off > 0; off >>= 1) {
        sg += __shfl_xor(sg, off);
        sb += __shfl_xor(sb, off);
    }
    __shared__ float rs[4][2];
    if ((tid & 63) == 0) { rs[tid >> 6][0] = sg; rs[tid >> 6][1] = sb; }
    __syncthreads();
    if (tid == 0) {
        float a = 0.f, c = 0.f;
#pragma unroll
        for (int w = 0; w < 4; ++w) { a += rs[w][0]; c += rs[w][1]; }
        SG[p] = a;
        ZC[p] = c + bnet[p];
    }
}

// ---------------------------------------------------------------------------
// K2: bank[b][r] = dot(task[b], Wtok[r]) + btok[r]; ptok[b][d] likewise.
// ---------------------------------------------------------------------------
__global__ void prep_bank(const float* __restrict__ task,
                          const float* __restrict__ Wtok, const float* __restrict__ btok,
                          const float* __restrict__ Wptok, const float* __restrict__ bptok,
                          float* __restrict__ bank, float* __restrict__ ptok) {
    __shared__ float ti[32 * KK];
    const int tid = threadIdx.x;
    const int b0 = blockIdx.y * 32;
    for (int i = tid; i < 32 * KK; i += 256) ti[i] = task[b0 * KK + i];

    const int r = blockIdx.x * 256 + tid;
    const bool isbank = (r < PP * DD);
    const int rr = isbank ? r : (r - PP * DD);
    const float* __restrict__ W = isbank ? Wtok : Wptok;
    const float bias = isbank ? btok[r] : bptok[rr];

    float w[KK];
#pragma unroll
    for (int k = 0; k < KK; ++k) w[k] = W[rr * KK + k];

    __syncthreads();
#pragma unroll 1
    for (int bb = 0; bb < 32; ++bb) {
        float acc = bias;
#pragma unroll
        for (int k = 0; k < KK; ++k) acc = fmaf(ti[bb * KK + k], w[k], acc);
        const int b = b0 + bb;
        if (isbank) bank[b * (PP * DD) + r] = acc;
        else        ptok[b * DD + rr]       = acc;
    }
}

// ---------------------------------------------------------------------------
// K3 (fused_persist): ONE block per b (256 blocks, all resident). 448 thr.
// Persistent regs: ptk, gf[10], bank[10] (loaded once, amortized x64 rows).
// 64 rows processed as 8 groups of 8 with double-buffered X bursts: group
// g+1's 8 loads are issued BEFORE group g's compute, and the two per-group
// barriers are RAW (lgkmcnt-only, R13-proven) so the burst stays in flight.
// Memory queue never drains -> continuous HBM issue.
// ---------------------------------------------------------------------------
__global__ __launch_bounds__(448, 1) void fused_persist(
    const float* __restrict__ X, const float* __restrict__ BANK,
    const float* __restrict__ PTOK, const float* __restrict__ GF,
    const float* __restrict__ SG, const float* __restrict__ ZC,
    float* __restrict__ OUT) {
    const int tid = threadIdx.x;
    const int b = blockIdx.x;

    const float4* __restrict__ X4 = (const float4*)X;
    const float4* __restrict__ B4 = (const float4*)BANK;
    const float4* __restrict__ G4 = (const float4*)GF;
    const float4* __restrict__ P4 = (const float4*)PTOK;
    float4* __restrict__ O4 = (float4*)OUT;

    __shared__ float red[GR][NGRP][12];
    __shared__ float wlds[GR][PP];

    const size_t rstride = (size_t)BB * DQ;
    const size_t base0 = (size_t)b * DQ + tid;

    // ---- persistent state: loaded once for the whole block ----
    const float4 ptk = P4[base0];
    float4 gf[PP];
#pragma unroll
    for (int p = 0; p < PP; ++p) gf[p] = G4[(size_t)p * DQ + tid];
    float4 bk[PP];
#pragma unroll
    for (int p = 0; p < PP; ++p) bk[p] = B4[((size_t)b * PP + p) * DQ + tid];

    const bool writer = ((tid & 15) == 15);
    const int g16 = tid >> 4;

    float4 x0[GR], x1[GR];

#define BURST(XN, GN)                                                              \
    {                                                                              \
        _Pragma("unroll")                                                          \
        for (int r = 0; r < GR; ++r)                                               \
            XN[r] = X4[((size_t)((GN) * GR + r) * BB + b) * DQ + tid];             \
        __builtin_amdgcn_sched_barrier(0);                                         \
    }

#define BARRIER_RAW()                                                              \
    asm volatile("s_waitcnt lgkmcnt(0)" ::: "memory");                             \
    __builtin_amdgcn_sched_barrier(0);                                             \
    __builtin_amdgcn_s_barrier();                                                  \
    __builtin_amdgcn_sched_barrier(0);

#define PHASE1(XC)                                                                 \
    {                                                                              \
        _Pragma("unroll")                                                          \
        for (int r = 0; r < GR; ++r) {                                             \
            float4 t;                                                              \
            t.x = XC[r].x + ptk.x; t.y = XC[r].y + ptk.y;                          \
            t.z = XC[r].z + ptk.z; t.w = XC[r].w + ptk.w;                          \
            float s1 = t.x + t.y + t.z + t.w;                                      \
            float s2 = t.x * t.x;                                                  \
            s2 = fmaf(t.y, t.y, s2); s2 = fmaf(t.z, t.z, s2);                      \
            s2 = fmaf(t.w, t.w, s2);                                               \
            float a[PP];                                                           \
            _Pragma("unroll")                                                      \
            for (int p = 0; p < PP; ++p) {                                         \
                float v = t.x * gf[p].x;                                           \
                v = fmaf(t.y, gf[p].y, v);                                         \
                v = fmaf(t.z, gf[p].z, v);                                         \
                v = fmaf(t.w, gf[p].w, v);                                         \
                a[p] = v;                                                          \
            }                                                                      \
            s1 = group16_sum_dpp(s1);                                              \
            s2 = group16_sum_dpp(s2);                                              \
            _Pragma("unroll")                                                      \
            for (int p = 0; p < PP; ++p) a[p] = group16_sum_dpp(a[p]);             \
            if (writer) {                                                          \
                float4* dst = (float4*)&red[r][g16][0];                            \
                dst[0] = make_float4(s1, s2, a[0], a[1]);                          \
                dst[1] = make_float4(a[2], a[3], a[4], a[5]);                      \
                dst[2] = make_float4(a[6], a[7], a[8], a[9]);                      \
            }                                                                      \
        }                                                                          \
    }

#define FINALIZE()                                                                 \
    if (tid < GR * 16) {                                                           \
        const int row = tid >> 4;                                                  \
        const int v = tid & 15;                                                    \
        float f = 0.f;                                                             \
        if (v < 12) {                                                              \
            _Pragma("unroll")                                                      \
            for (int q = 0; q < NGRP; ++q) f += red[row][q][v];                    \
        }                                                                          \
        const int bse = (tid & 63) & ~15;                                          \
        const float mu = __shfl(f, bse)     * (1.0f / (float)DD);                  \
        const float ms = __shfl(f, bse + 1) * (1.0f / (float)DD);                  \
        const float istd = rsqrtf(ms - mu * mu + 1e-5f);                           \
        if (v >= 2 && v < 12) {                                                    \
            const int p = v - 2;                                                   \
            const float z = istd * (f - mu * SG[p]) + ZC[p];                       \
            wlds[row][p] = 1.0f / (1.0f + __expf(-z));                             \
        }                                                                          \
    }

#define PHASE2(XC, GN)                                                             \
    {                                                                              \
        _Pragma("unroll")                                                          \
        for (int r = 0; r < GR; ++r) {                                             \
            float4 acc = XC[r];                                                    \
            _Pragma("unroll")                                                      \
            for (int p = 0; p < PP; ++p) {                                         \
                const float wv = wlds[r][p];                                       \
                acc.x = fmaf(wv, bk[p].x, acc.x);                                  \
                acc.y = fmaf(wv, bk[p].y, acc.y);                                  \
                acc.z = fmaf(wv, bk[p].z, acc.z);                                  \
                acc.w = fmaf(wv, bk[p].w, acc.w);                                  \
            }                                                                      \
            O4[((size_t)((GN) * GR + r) * BB + b) * DQ + tid] = acc;               \
        }                                                                          \
    }

#define GROUP(XC, XN, GN, DO_NEXT)                                                 \
    if (DO_NEXT) { BURST(XN, (GN) + 1) }                                           \
    PHASE1(XC)                                                                     \
    BARRIER_RAW()                                                                  \
    FINALIZE()                                                                     \
    BARRIER_RAW()                                                                  \
    PHASE2(XC, GN)

    // ---- prologue: first burst ----
    BURST(x0, 0)

    GROUP(x0, x1, 0, true)
    GROUP(x1, x0, 1, true)
    GROUP(x0, x1, 2, true)
    GROUP(x1, x0, 3, true)
    GROUP(x0, x1, 4, true)
    GROUP(x1, x0, 5, true)
    GROUP(x0, x1, 6, true)
    GROUP(x1, x0, 7, false)

#undef GROUP
#undef PHASE2
#undef FINALIZE
#undef PHASE1
#undef BARRIER_RAW
#undef BURST
}

// ---------------------------------------------------------------------------
extern "C" void kernel_launch(void* const* d_in, const int* in_sizes, int n_in,
                              void* d_out, int out_size, void* d_ws, size_t ws_size,
                              hipStream_t stream) {
    const float* X     = (const float*)d_in[0];
    const float* task  = (const float*)d_in[1];
    const float* Wtok  = (const float*)d_in[2];
    const float* btok  = (const float*)d_in[3];
    const float* Wptok = (const float*)d_in[4];
    const float* bptok = (const float*)d_in[5];
    const float* gamma = (const float*)d_in[6];
    const float* beta  = (const float*)d_in[7];
    const float* Wnet  = (const float*)d_in[8];
    const float* bnet  = (const float*)d_in[9];
    float* out = (float*)d_out;

    float* ws = (float*)d_ws;
    float* bank = ws;                                  // B*P*D = 4,587,520
    float* ptok = bank + (size_t)BB * PP * DD;         // B*D   =   458,752
    float* GF   = ptok + (size_t)BB * DD;              // P*D   =    17,920
    float* SG   = GF + PP * DD;                        // P
    float* ZC   = SG + PP;                             // P

    prep_gf<<<PP, 256, 0, stream>>>(gamma, beta, Wnet, bnet, GF, SG, ZC);
    prep_bank<<<dim3(77, 8), 256, 0, stream>>>(task, Wtok, btok, Wptok, bptok, bank, ptok);
    fused_persist<<<BB, 448, 0, stream>>>(X, bank, ptok, GF, SG, ZC, out);
}